// Round 12
// baseline (193.244 us; speedup 1.0000x reference)
//
#include <hip/hip_runtime.h>

// ---------- types / helpers ----------
typedef _Float16 f16x8 __attribute__((ext_vector_type(8)));
typedef float f32x4 __attribute__((ext_vector_type(4)));
typedef const __attribute__((address_space(1))) void* as1_cvp;
typedef __attribute__((address_space(3))) void* as3_vp;

#define LOG2E2 2.88539008177793f   // 2*log2(e)

__device__ __forceinline__ float tanh_fast(float x){
  float e = __builtin_amdgcn_exp2f(x * LOG2E2);
  return 1.f - 2.f * __builtin_amdgcn_rcpf(1.f + e);
}
__device__ __forceinline__ unsigned short f2h(float f){
  return __builtin_bit_cast(unsigned short, (_Float16)f);
}
__device__ __forceinline__ float h2f(unsigned short u){
  return (float)__builtin_bit_cast(_Float16, u);
}
__device__ __forceinline__ f32x4 mfma16(f16x8 a, f16x8 b, f32x4 c){
  return __builtin_amdgcn_mfma_f32_16x16x32_f16(a, b, c, 0, 0, 0);
}
__device__ __forceinline__ f16x8 ldsA(const unsigned short* buf, int rb, int s, int lane){
  return *(const f16x8*)(buf + (rb*16 + (lane&15))*128 + s*32 + ((lane>>4)<<3));
}

// ---------- PREP ----------
// Also zeroes accg (blocks 0..255, 16KB each) and cnt[64] (block 848).
// hw2 -> wt2 tiles: tile(i,chalf) 16KB contiguous, layout [kg(16)][c64(64)][k&7(8)].
__global__ __launch_bounds__(256) void prep_kernel(
    const float* __restrict__ obs, const float* __restrict__ hw1,
    const float* __restrict__ hb1, const float* __restrict__ hw2,
    const float* __restrict__ vw1, const float* __restrict__ vw2,
    const float* __restrict__ aw1, const float* __restrict__ aw2,
    unsigned short* __restrict__ wt2, unsigned short* __restrict__ vw1t,
    unsigned short* __restrict__ vw2t, unsigned short* __restrict__ aw1t,
    unsigned short* __restrict__ aw2t, unsigned short* __restrict__ h16,
    float* __restrict__ xT, float* __restrict__ accg, int* __restrict__ cnt){
  int b = blockIdx.x, t = threadIdx.x;
  if (b < 256){
    f32x4 z = {0.f,0.f,0.f,0.f};
    #pragma unroll
    for (int i=t; i<1024; i+=256) ((f32x4*)accg)[(size_t)b*1024 + i] = z;
  }
  if (b == 848 && t < 64) cnt[t] = 0;

  if (b < 768){
    __shared__ float xp[64][33];          // [col-offset][k-offset]
    int i = b >> 3, chalf = (b&7) >> 2, kq = b & 3;
    int c0 = i*128 + chalf*64, r0 = kq*32;
    int tx = t & 63, j0 = t >> 6;
    #pragma unroll
    for (int j = j0; j < 32; j += 4)
      xp[tx][j] = hw2[(size_t)(r0+j)*12288 + c0 + tx];
    __syncthreads();
    int c = t & 63, kgl = t >> 6;
    unsigned short us[8];
    #pragma unroll
    for (int q=0;q<8;++q) us[q] = f2h(xp[c][kgl*8 + q]);
    size_t dst = (size_t)(i*2 + chalf)*8192 + (size_t)(kq*4 + kgl)*512 + c*8;
    *(uint4*)(wt2 + dst) = *(uint4*)us;
  } else if (b < 848){
    __shared__ float tile[32][33];
    const float* in; unsigned short* out; int R, bx, by;
    if (b < 784)      { int q=b-768; in=vw1; out=vw1t; R=128; bx=q&3; by=q>>2; }
    else if (b < 800) { int q=b-784; in=vw2; out=vw2t; R=128; bx=q&3; by=q>>2; }
    else if (b < 832) { int q=b-800; in=aw1; out=aw1t; R=256; bx=q&3; by=q>>2; }
    else              { int q=b-832; in=aw2; out=aw2t; R=128; bx=q&3; by=q>>2; }
    int c0=bx*32, r0=by*32, tx=t&31, ty=t>>5;
    #pragma unroll
    for (int j=ty; j<32; j+=8) tile[j][tx] = in[(size_t)(r0+j)*128 + c0 + tx];
    __syncthreads();
    #pragma unroll
    for (int j=ty; j<32; j+=8) out[(size_t)(c0+j)*R + r0 + tx] = f2h(tile[tx][j]);
  } else {
    __shared__ float w_s[96*128];
    __shared__ float x_s[32*97];
    __shared__ float b_s[128];
    int n0 = (b-848)*32;
    for (int idx=t; idx<96*128; idx+=256) w_s[idx] = hw1[idx];
    if (t < 128) b_s[t] = hb1[t];
    for (int idx=t; idx<32*96; idx+=256){
      int r = idx/96, i = idx - r*96;
      int n = n0 + r; int bb = n>>3, l = n&7;
      x_s[r*97+i] = (i<64) ? obs[bb*360 + i] : obs[bb*360 + 104 + (l<<5) + (i-64)];
    }
    __syncthreads();
    for (int e=t; e<96*32; e+=256){
      int i = e>>5, r = e&31;
      xT[(size_t)i*8192 + n0 + r] = x_s[r*97 + i];
    }
    for (int e=t; e<32*128; e+=256){
      int r = e>>7, o = e&127;
      float acc = b_s[o];
      const float* xr = &x_s[r*97];
      #pragma unroll 4
      for (int i=0;i<96;++i) acc = fmaf(xr[i], w_s[i*128+o], acc);
      h16[(size_t)(n0+r)*128 + o] = f2h(tanh_fast(acc));
    }
  }
}

// ---------- K2: pipelined hypernet GEMM + tanh + x-contraction + epilogue ----
// grid 1024: bid = rt*16 + chalf*8 + iseg. Block 256 thr: 128 rows x 64 cols x 12 i.
// LDS 40448B -> 4 blocks/CU exactly (grid = 4 x 256, zero tail).
// Last block per rt (device counter) computes emb16 + mean16 from accg
// (reads via atomicAdd(p,0.f): coherent with the atomic writes by construction).
__device__ __forceinline__ void stage_tile(const unsigned short* gsrc,
                                           unsigned short* lbuf, int t){
  const unsigned short* g = gsrc + t*8;
  unsigned short* l = lbuf + t*8;
  #pragma unroll
  for (int p=0;p<4;++p)
    __builtin_amdgcn_global_load_lds((as1_cvp)(g + p*2048), (as3_vp)(l + p*2048), 16, 0, 0);
}

__global__ __launch_bounds__(256) __attribute__((amdgpu_waves_per_eu(3,4)))
void k2_hyper(const float* __restrict__ xT, const unsigned short* __restrict__ h16,
              const unsigned short* __restrict__ wt2, const float* __restrict__ hb2,
              float* __restrict__ accg, int* __restrict__ cnt,
              unsigned short* __restrict__ emb16, unsigned short* __restrict__ mean16){
  __shared__ char smem[40448];
  unsigned short* bts0 = (unsigned short*)smem;            // 16KB tile buf 0
  unsigned short* bts1 = (unsigned short*)(smem + 16384);  // 16KB tile buf 1
  float* x_s           = (float*)(smem + 32768);           // 12x128 f32 = 6KB
  unsigned short* bias_s = (unsigned short*)(smem + 38912);// 12x64 f16 (pre-scaled)
  int* lastflag        = (int*)(smem + 32768);             // alias x_s (post-loop)
  unsigned short* es   = (unsigned short*)smem;            // epilogue 128x128 f16

  int t = threadIdx.x, lane = t & 63, rg = t >> 6;
  int bid = blockIdx.x;
  int rt = bid >> 4, chalf = (bid >> 3) & 1, iseg = bid & 7;
  int R0 = rt*128, C0 = chalf*64, ibase = iseg*12;
  int cl   = lane & 15;
  int g    = lane >> 4;
  int kof  = g << 3;
  int rloc = g << 2;

  stage_tile(wt2 + (size_t)(ibase*2 + chalf)*8192, bts0, t);

  for (int idx=t; idx<12*128; idx+=256){
    int il = idx>>7, r = idx&127;
    x_s[idx] = xT[(size_t)(ibase+il)*8192 + R0 + r];
  }
  for (int idx=t; idx<12*64; idx+=256){
    int il = idx>>6, c = idx&63;
    bias_s[idx] = f2h(hb2[(ibase+il)*128 + C0 + c] * LOG2E2);
  }

  // A fragments: this wave's 32 rows, i-invariant
  f16x8 af[2][4];
  #pragma unroll
  for (int rb=0; rb<2; ++rb)
    #pragma unroll
    for (int s=0; s<4; ++s)
      af[rb][s] = *(const f16x8*)(h16 + (size_t)(R0 + rg*32 + rb*16 + cl)*128 + s*32 + kof);

  float facc[2][4][4];
  #pragma unroll
  for (int rb=0;rb<2;++rb)
    #pragma unroll
    for (int ch=0;ch<4;++ch)
      #pragma unroll
      for (int reg=0;reg<4;++reg) facc[rb][ch][reg] = 0.f;

  asm volatile("s_waitcnt vmcnt(0) lgkmcnt(0)" ::: "memory");
  __builtin_amdgcn_s_barrier();   // tile0 + x_s + bias_s ready
  __builtin_amdgcn_sched_barrier(0);

  const f32x4 zero4 = {0.f,0.f,0.f,0.f};

  for (int it=0; it<12; ++it){
    const unsigned short* lb = (it & 1) ? bts1 : bts0;
    if (it < 11)
      stage_tile(wt2 + (size_t)((ibase+it+1)*2 + chalf)*8192, (it&1)?bts0:bts1, t);

    f32x4 xa = *(const f32x4*)(x_s + it*128 + rg*32 + rloc);
    f32x4 xb = *(const f32x4*)(x_s + it*128 + rg*32 + 16 + rloc);
    #pragma unroll
    for (int ch=0; ch<4; ++ch){
      int c64 = ch*16 + cl;
      const unsigned short* bp = lb + c64*8 + g*512;   // [kg][c64][k&7]: linear 16B
      f16x8 b0 = *(const f16x8*)(bp);
      f16x8 b1 = *(const f16x8*)(bp + 2048);
      f16x8 b2 = *(const f16x8*)(bp + 4096);
      f16x8 b3 = *(const f16x8*)(bp + 6144);
      float bi2 = h2f(bias_s[it*64 + c64]);
      f32x4 a0 = zero4, a1 = zero4;
      a0 = mfma16(af[0][0], b0, a0); a1 = mfma16(af[1][0], b0, a1);
      a0 = mfma16(af[0][1], b1, a0); a1 = mfma16(af[1][1], b1, a1);
      a0 = mfma16(af[0][2], b2, a0); a1 = mfma16(af[1][2], b2, a1);
      a0 = mfma16(af[0][3], b3, a0); a1 = mfma16(af[1][3], b3, a1);
      #pragma unroll
      for (int reg=0;reg<4;++reg){
        float e0 = __builtin_amdgcn_exp2f(fmaf(a0[reg], LOG2E2, bi2));
        float e1 = __builtin_amdgcn_exp2f(fmaf(a1[reg], LOG2E2, bi2));
        float t0 = 1.f - 2.f*__builtin_amdgcn_rcpf(1.f + e0);
        float t1 = 1.f - 2.f*__builtin_amdgcn_rcpf(1.f + e1);
        facc[0][ch][reg] = fmaf(xa[reg], t0, facc[0][ch][reg]);
        facc[1][ch][reg] = fmaf(xb[reg], t1, facc[1][ch][reg]);
      }
    }
    asm volatile("s_waitcnt vmcnt(0)" ::: "memory");  // next tile landed
    __builtin_amdgcn_s_barrier();                     // all waves done with lb
    __builtin_amdgcn_sched_barrier(0);
  }

  #pragma unroll
  for (int rb=0; rb<2; ++rb)
    #pragma unroll
    for (int ch=0; ch<4; ++ch)
      #pragma unroll
      for (int reg=0; reg<4; ++reg)
        atomicAdd(&accg[(size_t)(R0 + rg*32 + rb*16 + rloc + reg)*128 + C0 + ch*16 + cl],
                  facc[rb][ch][reg]);

  // ----- last-block-per-rt epilogue: emb16 + mean16 -----
  __threadfence();
  __syncthreads();
  if (t == 0) *lastflag = (atomicAdd(&cnt[rt], 1) == 15) ? 1 : 0;
  __syncthreads();
  if (!*lastflag) return;

  for (int idx=t; idx<128*128; idx+=256){
    int row = idx>>7, col = idx&127;
    float v = atomicAdd(&accg[(size_t)(R0+row)*128 + col], 0.f);
    float e = tanh_fast(v);
    unsigned short h = f2h(e);
    es[idx] = h;
    emb16[(size_t)(R0+row)*128 + col] = h;
  }
  __syncthreads();
  for (int task=t; task<16*128; task+=256){
    int bl = task>>7, col = task&127;
    float m = 0.f;
    #pragma unroll
    for (int l=0;l<8;++l) m += h2f(es[(bl*8+l)*128 + col]);
    mean16[(size_t)(rt*16 + bl)*128 + col] = f2h(m * 0.125f);
  }
}

// ---------- K4: fused MLP chain + softmax + final ----------
template<int KS>
__device__ __forceinline__ void stage(const unsigned short* inA, const unsigned short* inB,
    const unsigned short* wt, const float* bias, unsigned short* outb, int w, int lane){
  #pragma unroll
  for (int obl=0; obl<2; ++obl){
    int col = ((w*2+obl)<<4) + (lane&15);
    f32x4 a0 = {0.f,0.f,0.f,0.f}, a1v = {0.f,0.f,0.f,0.f};
    #pragma unroll
    for (int s=0;s<KS;++s){
      f16x8 bfr = *(const f16x8*)(wt + (size_t)col*(KS*32) + s*32 + ((lane>>4)<<3));
      f16x8 aa0, aa1;
      if (KS==8 && s>=4){ aa0 = ldsA(inB,0,s-4,lane); aa1 = ldsA(inB,1,s-4,lane); }
      else              { aa0 = ldsA(inA,0,s,lane);   aa1 = ldsA(inA,1,s,lane);   }
      a0  = mfma16(aa0, bfr, a0);
      a1v = mfma16(aa1, bfr, a1v);
    }
    float bb = bias[col];
    #pragma unroll
    for (int reg=0;reg<4;++reg){
      int r0 = ((lane>>4)<<2) + reg;
      outb[r0*128 + col]      = f2h(tanh_fast(a0[reg] + bb));
      outb[(16+r0)*128 + col] = f2h(tanh_fast(a1v[reg] + bb));
    }
  }
}

__global__ __launch_bounds__(256) void k4_mlp(
    const unsigned short* __restrict__ emb16, const unsigned short* __restrict__ mean16,
    const unsigned short* __restrict__ vw1t, const unsigned short* __restrict__ vw2t,
    const unsigned short* __restrict__ aw1t, const unsigned short* __restrict__ aw2t,
    const float* __restrict__ vb1, const float* __restrict__ vb2,
    const float* __restrict__ ab1, const float* __restrict__ ab2,
    const float* __restrict__ aw3, const float* __restrict__ ab3,
    float* __restrict__ outp){
  __shared__ unsigned short bufE[32*128];
  __shared__ unsigned short bufM[32*128];
  __shared__ unsigned short bufA[32*128];
  __shared__ float fin[4*128];
  __shared__ float lp[32*8];
  __shared__ float att_s[32];
  int t = threadIdx.x, lane = t&63, w = t>>6;
  int R0 = blockIdx.x*32;

  for (int idx=t; idx<512; idx+=256){
    int r = idx>>4, c8 = (idx&15)<<3;
    int n = R0 + r;
    *(uint4*)(bufE + r*128 + c8) = *(const uint4*)(emb16  + (size_t)n*128 + c8);
    *(uint4*)(bufM + r*128 + c8) = *(const uint4*)(mean16 + (size_t)(n & 1023)*128 + c8);
  }
  for (int idx=t; idx<512; idx+=256) fin[idx] = 0.f;
  __syncthreads();

  stage<8>(bufE, bufM, aw1t, ab1, bufA, w, lane);
  __syncthreads();
  stage<4>(bufA, nullptr, aw2t, ab2, bufM, w, lane);
  __syncthreads();
  {
    int r = t>>3, seg = t&7;
    float p = 0.f;
    const unsigned short* row = bufM + r*128 + seg*16;
    const float* w3 = aw3 + seg*16;
    #pragma unroll
    for (int k=0;k<16;++k) p += h2f(row[k]) * w3[k];
    lp[r*8+seg] = p;
  }
  __syncthreads();
  if (t < 4){
    float lg[8]; float mx = -1e30f;
    for (int l=0;l<8;++l){
      float s = ab3[0];
      #pragma unroll
      for (int sg=0;sg<8;++sg) s += lp[(t*8+l)*8+sg];
      lg[l] = s; mx = fmaxf(mx, s);
    }
    float sum = 0.f;
    for (int l=0;l<8;++l){ lg[l] = __builtin_amdgcn_exp2f((lg[l]-mx)*1.44269504089f); sum += lg[l]; }
    float inv = __builtin_amdgcn_rcpf(sum);
    for (int l=0;l<8;++l) att_s[t*8+l] = lg[l]*inv;
  }
  __syncthreads();
  stage<4>(bufE, nullptr, vw1t, vb1, bufA, w, lane);
  __syncthreads();
  {
    #pragma unroll
    for (int obl=0; obl<2; ++obl){
      int col = ((w*2+obl)<<4) + (lane&15);
      f32x4 a0 = {0.f,0.f,0.f,0.f}, a1v = {0.f,0.f,0.f,0.f};
      #pragma unroll
      for (int s=0;s<4;++s){
        f16x8 bfr = *(const f16x8*)(vw2t + (size_t)col*128 + s*32 + ((lane>>4)<<3));
        a0  = mfma16(ldsA(bufA,0,s,lane), bfr, a0);
        a1v = mfma16(ldsA(bufA,1,s,lane), bfr, a1v);
      }
      float bb = vb2[col];
      #pragma unroll
      for (int reg=0;reg<4;++reg){
        int r0 = ((lane>>4)<<2) + reg;
        float v0 = tanh_fast(a0[reg]+bb);
        float v1 = tanh_fast(a1v[reg]+bb);
        atomicAdd(&fin[((r0)>>3)*128 + col],    att_s[r0]    * v0);
        atomicAdd(&fin[((16+r0)>>3)*128 + col], att_s[16+r0] * v1);
      }
    }
  }
  __syncthreads();
  for (int idx=t; idx<512; idx+=256){
    int b_loc = idx>>7, o = idx&127;
    outp[(size_t)(R0/8 + b_loc)*128 + o] = fin[idx];
  }
}

// ---------- launch ----------
extern "C" void kernel_launch(void* const* d_in, const int* in_sizes, int n_in,
                              void* d_out, int out_size, void* d_ws, size_t ws_size,
                              hipStream_t stream){
  const float* obs = (const float*)d_in[0];
  const float* hw1 = (const float*)d_in[3];
  const float* hb1 = (const float*)d_in[4];
  const float* hw2 = (const float*)d_in[5];
  const float* hb2 = (const float*)d_in[6];
  const float* vw1 = (const float*)d_in[7];
  const float* vb1 = (const float*)d_in[8];
  const float* vw2 = (const float*)d_in[9];
  const float* vb2 = (const float*)d_in[10];
  const float* aw1 = (const float*)d_in[11];
  const float* ab1 = (const float*)d_in[12];
  const float* aw2 = (const float*)d_in[13];
  const float* ab2 = (const float*)d_in[14];
  const float* aw3 = (const float*)d_in[15];
  const float* ab3 = (const float*)d_in[16];

  char* ws = (char*)d_ws;
  unsigned short* wt2    = (unsigned short*)(ws);             // 3,145,728 B
  unsigned short* h16    = (unsigned short*)(ws + 3145728);   // 2,097,152 B
  float*          accg   = (float*)        (ws + 5242880);    // 4,194,304 B
  float*          xT     = (float*)        (ws + 9437184);    // 3,145,728 B
  unsigned short* emb16  = (unsigned short*)(ws + 12582912);  // 2,097,152 B
  unsigned short* mean16 = (unsigned short*)(ws + 14680064);  //   262,144 B
  unsigned short* vw1t   = (unsigned short*)(ws + 14942208);  //    32,768 B
  unsigned short* vw2t   = (unsigned short*)(ws + 14974976);  //    32,768 B
  unsigned short* aw1t   = (unsigned short*)(ws + 15007744);  //    65,536 B
  unsigned short* aw2t   = (unsigned short*)(ws + 15073280);  //    32,768 B
  int*            cnt    = (int*)           (ws + 15106048);  //       256 B (end 15,106,304)
  float* outp = (float*)d_out;

  prep_kernel<<<1104, 256, 0, stream>>>(obs, hw1, hb1, hw2, vw1, vw2, aw1, aw2,
                                        wt2, vw1t, vw2t, aw1t, aw2t, h16, xT, accg, cnt);
  k2_hyper<<<1024, 256, 0, stream>>>(xT, h16, wt2, hb2, accg, cnt, emb16, mean16);
  k4_mlp<<<256, 256, 0, stream>>>(emb16, mean16, vw1t, vw2t, aw1t, aw2t,
                                  vb1, vb2, ab1, ab2, aw3, ab3, outp);
}

// Round 14
// 110.988 us; speedup vs baseline: 1.7411x; 1.7411x over previous
//
#include <hip/hip_runtime.h>

// ---------- types / helpers ----------
typedef _Float16 f16x8 __attribute__((ext_vector_type(8)));
typedef float f32x4 __attribute__((ext_vector_type(4)));
typedef const __attribute__((address_space(1))) void* as1_cvp;
typedef __attribute__((address_space(3))) void* as3_vp;

#define LOG2E2 2.88539008177793f   // 2*log2(e)

__device__ __forceinline__ float tanh_fast(float x){
  float e = __builtin_amdgcn_exp2f(x * LOG2E2);
  return 1.f - 2.f * __builtin_amdgcn_rcpf(1.f + e);
}
__device__ __forceinline__ unsigned short f2h(float f){
  return __builtin_bit_cast(unsigned short, (_Float16)f);
}
__device__ __forceinline__ float h2f(unsigned short u){
  return (float)__builtin_bit_cast(_Float16, u);
}
__device__ __forceinline__ f32x4 mfma16(f16x8 a, f16x8 b, f32x4 c){
  return __builtin_amdgcn_mfma_f32_16x16x32_f16(a, b, c, 0, 0, 0);
}
__device__ __forceinline__ f16x8 ldsA(const unsigned short* buf, int rb, int s, int lane){
  return *(const f16x8*)(buf + (rb*16 + (lane&15))*128 + s*32 + ((lane>>4)<<3));
}

// ---------- PREP ----------
// Zeroes accg (blocks 0..255). hw2 -> wt2 tiles: tile(i,chalf) 16KB contiguous,
// layout [kg(16)][c64(64)][k&7(8)] (k2 B-reads linear 16B/lane; writes coalesced).
__global__ __launch_bounds__(256) void prep_kernel(
    const float* __restrict__ obs, const float* __restrict__ hw1,
    const float* __restrict__ hb1, const float* __restrict__ hw2,
    const float* __restrict__ vw1, const float* __restrict__ vw2,
    const float* __restrict__ aw1, const float* __restrict__ aw2,
    unsigned short* __restrict__ wt2, unsigned short* __restrict__ vw1t,
    unsigned short* __restrict__ vw2t, unsigned short* __restrict__ aw1t,
    unsigned short* __restrict__ aw2t, unsigned short* __restrict__ h16,
    float* __restrict__ xT, float* __restrict__ accg){
  int b = blockIdx.x, t = threadIdx.x;
  if (b < 256){
    f32x4 z = {0.f,0.f,0.f,0.f};
    #pragma unroll
    for (int i=t; i<1024; i+=256) ((f32x4*)accg)[(size_t)b*1024 + i] = z;
  }

  if (b < 768){
    __shared__ float xp[64][33];          // [col-offset][k-offset]
    int i = b >> 3, chalf = (b&7) >> 2, kq = b & 3;
    int c0 = i*128 + chalf*64, r0 = kq*32;
    int tx = t & 63, j0 = t >> 6;
    #pragma unroll
    for (int j = j0; j < 32; j += 4)
      xp[tx][j] = hw2[(size_t)(r0+j)*12288 + c0 + tx];
    __syncthreads();
    int c = t & 63, kgl = t >> 6;
    unsigned short us[8];
    #pragma unroll
    for (int q=0;q<8;++q) us[q] = f2h(xp[c][kgl*8 + q]);
    size_t dst = (size_t)(i*2 + chalf)*8192 + (size_t)(kq*4 + kgl)*512 + c*8;
    *(uint4*)(wt2 + dst) = *(uint4*)us;
  } else if (b < 848){
    __shared__ float tile[32][33];
    const float* in; unsigned short* out; int R, bx, by;
    if (b < 784)      { int q=b-768; in=vw1; out=vw1t; R=128; bx=q&3; by=q>>2; }
    else if (b < 800) { int q=b-784; in=vw2; out=vw2t; R=128; bx=q&3; by=q>>2; }
    else if (b < 832) { int q=b-800; in=aw1; out=aw1t; R=256; bx=q&3; by=q>>2; }
    else              { int q=b-832; in=aw2; out=aw2t; R=128; bx=q&3; by=q>>2; }
    int c0=bx*32, r0=by*32, tx=t&31, ty=t>>5;
    #pragma unroll
    for (int j=ty; j<32; j+=8) tile[j][tx] = in[(size_t)(r0+j)*128 + c0 + tx];
    __syncthreads();
    #pragma unroll
    for (int j=ty; j<32; j+=8) out[(size_t)(c0+j)*R + r0 + tx] = f2h(tile[tx][j]);
  } else {
    __shared__ float w_s[96*128];
    __shared__ float x_s[32*97];
    __shared__ float b_s[128];
    int n0 = (b-848)*32;
    for (int idx=t; idx<96*128; idx+=256) w_s[idx] = hw1[idx];
    if (t < 128) b_s[t] = hb1[t];
    for (int idx=t; idx<32*96; idx+=256){
      int r = idx/96, i = idx - r*96;
      int n = n0 + r; int bb = n>>3, l = n&7;
      x_s[r*97+i] = (i<64) ? obs[bb*360 + i] : obs[bb*360 + 104 + (l<<5) + (i-64)];
    }
    __syncthreads();
    for (int e=t; e<96*32; e+=256){
      int i = e>>5, r = e&31;
      xT[(size_t)i*8192 + n0 + r] = x_s[r*97 + i];
    }
    for (int e=t; e<32*128; e+=256){
      int r = e>>7, o = e&127;
      float acc = b_s[o];
      const float* xr = &x_s[r*97];
      #pragma unroll 4
      for (int i=0;i<96;++i) acc = fmaf(xr[i], w_s[i*128+o], acc);
      h16[(size_t)(n0+r)*128 + o] = f2h(tanh_fast(acc));
    }
  }
}

// ---------- K2: pipelined hypernet GEMM + tanh + x-contraction ----------
// grid 1024: bid = rt*16 + chalf*8 + iseg. Block 256 thr: 128 rows x 64 cols x 12 i.
// LDS 40448B -> exactly 4 blocks/CU (grid = 4 x 256, zero tail). Intrinsic MFMA
// (compiler-managed hazards). Inner loop zero-VMEM; manual vmcnt(0)+raw barrier.
__device__ __forceinline__ void stage_tile(const unsigned short* gsrc,
                                           unsigned short* lbuf, int t){
  const unsigned short* g = gsrc + t*8;
  unsigned short* l = lbuf + t*8;
  #pragma unroll
  for (int p=0;p<4;++p)
    __builtin_amdgcn_global_load_lds((as1_cvp)(g + p*2048), (as3_vp)(l + p*2048), 16, 0, 0);
}

__global__ __launch_bounds__(256) __attribute__((amdgpu_waves_per_eu(3,4)))
void k2_hyper(const float* __restrict__ xT, const unsigned short* __restrict__ h16,
              const unsigned short* __restrict__ wt2, const float* __restrict__ hb2,
              float* __restrict__ accg){
  __shared__ char smem[40448];
  unsigned short* bts0 = (unsigned short*)smem;            // 16KB tile buf 0
  unsigned short* bts1 = (unsigned short*)(smem + 16384);  // 16KB tile buf 1
  float* x_s           = (float*)(smem + 32768);           // 12x128 f32 = 6KB
  unsigned short* bias_s = (unsigned short*)(smem + 38912);// 12x64 f16 (pre-scaled)

  int t = threadIdx.x, lane = t & 63, rg = t >> 6;
  int bid = blockIdx.x;
  int rt = bid >> 4, chalf = (bid >> 3) & 1, iseg = bid & 7;
  int R0 = rt*128, C0 = chalf*64, ibase = iseg*12;
  int cl   = lane & 15;
  int g    = lane >> 4;
  int kof  = g << 3;
  int rloc = g << 2;

  stage_tile(wt2 + (size_t)(ibase*2 + chalf)*8192, bts0, t);

  for (int idx=t; idx<12*128; idx+=256){
    int il = idx>>7, r = idx&127;
    x_s[idx] = xT[(size_t)(ibase+il)*8192 + R0 + r];
  }
  for (int idx=t; idx<12*64; idx+=256){
    int il = idx>>6, c = idx&63;
    bias_s[idx] = f2h(hb2[(ibase+il)*128 + C0 + c] * LOG2E2);
  }

  // A fragments: this wave's 32 rows, i-invariant
  f16x8 af[2][4];
  #pragma unroll
  for (int rb=0; rb<2; ++rb)
    #pragma unroll
    for (int s=0; s<4; ++s)
      af[rb][s] = *(const f16x8*)(h16 + (size_t)(R0 + rg*32 + rb*16 + cl)*128 + s*32 + kof);

  float facc[2][4][4];
  #pragma unroll
  for (int rb=0;rb<2;++rb)
    #pragma unroll
    for (int ch=0;ch<4;++ch)
      #pragma unroll
      for (int reg=0;reg<4;++reg) facc[rb][ch][reg] = 0.f;

  asm volatile("s_waitcnt vmcnt(0) lgkmcnt(0)" ::: "memory");
  __builtin_amdgcn_s_barrier();   // tile0 + x_s + bias_s ready
  __builtin_amdgcn_sched_barrier(0);

  const f32x4 zero4 = {0.f,0.f,0.f,0.f};

  for (int it=0; it<12; ++it){
    const unsigned short* lb = (it & 1) ? bts1 : bts0;
    if (it < 11)
      stage_tile(wt2 + (size_t)((ibase+it+1)*2 + chalf)*8192, (it&1)?bts0:bts1, t);

    f32x4 xa = *(const f32x4*)(x_s + it*128 + rg*32 + rloc);
    f32x4 xb = *(const f32x4*)(x_s + it*128 + rg*32 + 16 + rloc);
    #pragma unroll
    for (int ch=0; ch<4; ++ch){
      int c64 = ch*16 + cl;
      const unsigned short* bp = lb + c64*8 + g*512;   // [kg][c64][k&7]: linear 16B
      f16x8 b0 = *(const f16x8*)(bp);
      f16x8 b1 = *(const f16x8*)(bp + 2048);
      f16x8 b2 = *(const f16x8*)(bp + 4096);
      f16x8 b3 = *(const f16x8*)(bp + 6144);
      float bi2 = h2f(bias_s[it*64 + c64]);
      f32x4 a0 = zero4, a1 = zero4;
      a0 = mfma16(af[0][0], b0, a0); a1 = mfma16(af[1][0], b0, a1);
      a0 = mfma16(af[0][1], b1, a0); a1 = mfma16(af[1][1], b1, a1);
      a0 = mfma16(af[0][2], b2, a0); a1 = mfma16(af[1][2], b2, a1);
      a0 = mfma16(af[0][3], b3, a0); a1 = mfma16(af[1][3], b3, a1);
      #pragma unroll
      for (int reg=0;reg<4;++reg){
        float e0 = __builtin_amdgcn_exp2f(fmaf(a0[reg], LOG2E2, bi2));
        float e1 = __builtin_amdgcn_exp2f(fmaf(a1[reg], LOG2E2, bi2));
        float t0 = 1.f - 2.f*__builtin_amdgcn_rcpf(1.f + e0);
        float t1 = 1.f - 2.f*__builtin_amdgcn_rcpf(1.f + e1);
        facc[0][ch][reg] = fmaf(xa[reg], t0, facc[0][ch][reg]);
        facc[1][ch][reg] = fmaf(xb[reg], t1, facc[1][ch][reg]);
      }
    }
    asm volatile("s_waitcnt vmcnt(0)" ::: "memory");  // next tile landed
    __builtin_amdgcn_s_barrier();                     // all waves done with lb
    __builtin_amdgcn_sched_barrier(0);
  }

  #pragma unroll
  for (int rb=0; rb<2; ++rb)
    #pragma unroll
    for (int ch=0; ch<4; ++ch)
      #pragma unroll
      for (int reg=0; reg<4; ++reg)
        atomicAdd(&accg[(size_t)(R0 + rg*32 + rb*16 + rloc + reg)*128 + C0 + ch*16 + cl],
                  facc[rb][ch][reg]);
}

// ---------- K3: per-batch landmark mean of tanh(accg) -> mean16 ----------
__global__ __launch_bounds__(256) void k3_mean(const float* __restrict__ accg,
    unsigned short* __restrict__ mean16){
  int t = threadIdx.x, B0 = blockIdx.x*4;
  for (int task=t; task<512; task+=256){
    int bl = task>>7, o = task&127;
    float m = 0.f;
    #pragma unroll
    for (int l=0;l<8;++l)
      m += tanh_fast(accg[(size_t)((B0 + bl)*8 + l)*128 + o]);
    mean16[(size_t)(B0 + bl)*128 + o] = f2h(m * 0.125f);
  }
}

// ---------- K4: emb from accg + fused MLP chain + softmax + final ----------
template<int KS>
__device__ __forceinline__ void stage(const unsigned short* inA, const unsigned short* inB,
    const unsigned short* wt, const float* bias, unsigned short* outb, int w, int lane){
  #pragma unroll
  for (int obl=0; obl<2; ++obl){
    int col = ((w*2+obl)<<4) + (lane&15);
    f32x4 a0 = {0.f,0.f,0.f,0.f}, a1v = {0.f,0.f,0.f,0.f};
    #pragma unroll
    for (int s=0;s<KS;++s){
      f16x8 bfr = *(const f16x8*)(wt + (size_t)col*(KS*32) + s*32 + ((lane>>4)<<3));
      f16x8 aa0, aa1;
      if (KS==8 && s>=4){ aa0 = ldsA(inB,0,s-4,lane); aa1 = ldsA(inB,1,s-4,lane); }
      else              { aa0 = ldsA(inA,0,s,lane);   aa1 = ldsA(inA,1,s,lane);   }
      a0  = mfma16(aa0, bfr, a0);
      a1v = mfma16(aa1, bfr, a1v);
    }
    float bb = bias[col];
    #pragma unroll
    for (int reg=0;reg<4;++reg){
      int r0 = ((lane>>4)<<2) + reg;
      outb[r0*128 + col]      = f2h(tanh_fast(a0[reg] + bb));
      outb[(16+r0)*128 + col] = f2h(tanh_fast(a1v[reg] + bb));
    }
  }
}

__global__ __launch_bounds__(256) void k4_mlp(
    const float* __restrict__ accg, const unsigned short* __restrict__ mean16,
    const unsigned short* __restrict__ vw1t, const unsigned short* __restrict__ vw2t,
    const unsigned short* __restrict__ aw1t, const unsigned short* __restrict__ aw2t,
    const float* __restrict__ vb1, const float* __restrict__ vb2,
    const float* __restrict__ ab1, const float* __restrict__ ab2,
    const float* __restrict__ aw3, const float* __restrict__ ab3,
    float* __restrict__ outp){
  __shared__ unsigned short bufE[32*128];
  __shared__ unsigned short bufM[32*128];
  __shared__ unsigned short bufA[32*128];
  __shared__ float fin[4*128];
  __shared__ float lp[32*8];
  __shared__ float att_s[32];
  int t = threadIdx.x, lane = t&63, w = t>>6;
  int R0 = blockIdx.x*32;

  for (int idx=t; idx<4096; idx+=256)
    bufE[idx] = f2h(tanh_fast(accg[(size_t)R0*128 + idx]));
  for (int idx=t; idx<512; idx+=256){
    int r = idx>>4, c8 = (idx&15)<<3;
    int n = R0 + r;
    *(uint4*)(bufM + r*128 + c8) = *(const uint4*)(mean16 + (size_t)(n & 1023)*128 + c8);
  }
  for (int idx=t; idx<512; idx+=256) fin[idx] = 0.f;
  __syncthreads();

  stage<8>(bufE, bufM, aw1t, ab1, bufA, w, lane);
  __syncthreads();
  stage<4>(bufA, nullptr, aw2t, ab2, bufM, w, lane);
  __syncthreads();
  {
    int r = t>>3, seg = t&7;
    float p = 0.f;
    const unsigned short* row = bufM + r*128 + seg*16;
    const float* w3 = aw3 + seg*16;
    #pragma unroll
    for (int k=0;k<16;++k) p += h2f(row[k]) * w3[k];
    lp[r*8+seg] = p;
  }
  __syncthreads();
  if (t < 4){
    float lg[8]; float mx = -1e30f;
    for (int l=0;l<8;++l){
      float s = ab3[0];
      #pragma unroll
      for (int sg=0;sg<8;++sg) s += lp[(t*8+l)*8+sg];
      lg[l] = s; mx = fmaxf(mx, s);
    }
    float sum = 0.f;
    for (int l=0;l<8;++l){ lg[l] = __builtin_amdgcn_exp2f((lg[l]-mx)*1.44269504089f); sum += lg[l]; }
    float inv = __builtin_amdgcn_rcpf(sum);
    for (int l=0;l<8;++l) att_s[t*8+l] = lg[l]*inv;
  }
  __syncthreads();
  stage<4>(bufE, nullptr, vw1t, vb1, bufA, w, lane);
  __syncthreads();
  {
    #pragma unroll
    for (int obl=0; obl<2; ++obl){
      int col = ((w*2+obl)<<4) + (lane&15);
      f32x4 a0 = {0.f,0.f,0.f,0.f}, a1v = {0.f,0.f,0.f,0.f};
      #pragma unroll
      for (int s=0;s<4;++s){
        f16x8 bfr = *(const f16x8*)(vw2t + (size_t)col*128 + s*32 + ((lane>>4)<<3));
        a0  = mfma16(ldsA(bufA,0,s,lane), bfr, a0);
        a1v = mfma16(ldsA(bufA,1,s,lane), bfr, a1v);
      }
      float bb = vb2[col];
      #pragma unroll
      for (int reg=0;reg<4;++reg){
        int r0 = ((lane>>4)<<2) + reg;
        float v0 = tanh_fast(a0[reg]+bb);
        float v1 = tanh_fast(a1v[reg]+bb);
        atomicAdd(&fin[((r0)>>3)*128 + col],    att_s[r0]    * v0);
        atomicAdd(&fin[((16+r0)>>3)*128 + col], att_s[16+r0] * v1);
      }
    }
  }
  __syncthreads();
  for (int idx=t; idx<512; idx+=256){
    int b_loc = idx>>7, o = idx&127;
    outp[(size_t)(R0/8 + b_loc)*128 + o] = fin[idx];
  }
}

// ---------- launch ----------
extern "C" void kernel_launch(void* const* d_in, const int* in_sizes, int n_in,
                              void* d_out, int out_size, void* d_ws, size_t ws_size,
                              hipStream_t stream){
  const float* obs = (const float*)d_in[0];
  const float* hw1 = (const float*)d_in[3];
  const float* hb1 = (const float*)d_in[4];
  const float* hw2 = (const float*)d_in[5];
  const float* hb2 = (const float*)d_in[6];
  const float* vw1 = (const float*)d_in[7];
  const float* vb1 = (const float*)d_in[8];
  const float* vw2 = (const float*)d_in[9];
  const float* vb2 = (const float*)d_in[10];
  const float* aw1 = (const float*)d_in[11];
  const float* ab1 = (const float*)d_in[12];
  const float* aw2 = (const float*)d_in[13];
  const float* ab2 = (const float*)d_in[14];
  const float* aw3 = (const float*)d_in[15];
  const float* ab3 = (const float*)d_in[16];

  char* ws = (char*)d_ws;
  unsigned short* wt2    = (unsigned short*)(ws);             // 3,145,728 B
  unsigned short* mean16 = (unsigned short*)(ws);             //   262,144 B (alias; wt2 dead after k2)
  unsigned short* h16    = (unsigned short*)(ws + 3145728);   // 2,097,152 B
  float*          accg   = (float*)        (ws + 5242880);    // 4,194,304 B
  float*          xT     = (float*)        (ws + 9437184);    // 3,145,728 B
  unsigned short* vw1t   = (unsigned short*)(ws + 12582912);  //    32,768 B
  unsigned short* vw2t   = (unsigned short*)(ws + 12615680);  //    32,768 B
  unsigned short* aw1t   = (unsigned short*)(ws + 12648448);  //    65,536 B
  unsigned short* aw2t   = (unsigned short*)(ws + 12713984);  //    32,768 B  (end 12,746,752)
  float* outp = (float*)d_out;

  prep_kernel<<<1104, 256, 0, stream>>>(obs, hw1, hb1, hw2, vw1, vw2, aw1, aw2,
                                        wt2, vw1t, vw2t, aw1t, aw2t, h16, xT, accg);
  k2_hyper<<<1024, 256, 0, stream>>>(xT, h16, wt2, hb2, accg);
  k3_mean<<<256, 256, 0, stream>>>(accg, mean16);
  k4_mlp<<<256, 256, 0, stream>>>(accg, mean16, vw1t, vw2t, aw1t, aw2t,
                                  vb1, vb2, ab1, ab2, aw3, ab3, outp);
}